// Round 8
// baseline (420.689 us; speedup 1.0000x reference)
//
#include <hip/hip_runtime.h>
#include <hip/hip_bf16.h>
#include <math.h>
#include <stdint.h>

// MHA pipeline: split_x + transpose weights (hi/lo bf16) + rope tables ->
// split QKV GEMM (3-term bf16 MFMA) -> rope+scatter (Q pre-scaled log2e/8) ->
// flash attention (256-thr blocks, 16 q-rows/wave, no spills, K dbuf LDS,
// V from L2, in-register P, bh-fast grid) -> out GEMM.

typedef __bf16 bf16;
typedef __bf16 bf16x8 __attribute__((ext_vector_type(8)));
typedef __bf16 bf16x4 __attribute__((ext_vector_type(4)));
typedef float f32x4 __attribute__((ext_vector_type(4)));

#define AS1 __attribute__((address_space(1)))
#define AS3 __attribute__((address_space(3)))

__device__ __forceinline__ void gload_lds16(const void* g, void* l) {
  __builtin_amdgcn_global_load_lds((const AS1 void*)g, (AS3 void*)l, 16, 0, 0);
}

__device__ __forceinline__ f32x4 mfma16(bf16x8 a, bf16x8 b, f32x4 c) {
  return __builtin_amdgcn_mfma_f32_16x16x32_bf16(a, b, c, 0, 0, 0);
}

#define S_LEN 2048
#define QSCALE 0.1803368801111144f  /* log2(e)/8 */

// ---------------- prep kernels ----------------

__global__ void k_split_x(const float* __restrict__ x, bf16* __restrict__ xh,
                          bf16* __restrict__ xl) {
  int i = blockIdx.x * 256 + threadIdx.x;
  float4 v = ((const float4*)x)[i];
  float vv[4] = {v.x, v.y, v.z, v.w};
  bf16x4 h, l;
#pragma unroll
  for (int j = 0; j < 4; j++) {
    bf16 hb = (bf16)vv[j];
    h[j] = hb;
    l[j] = (bf16)(vv[j] - (float)hb);
  }
  ((bf16x4*)xh)[i] = h;
  ((bf16x4*)xl)[i] = l;
}

__global__ void k_wt_qkv(const float* __restrict__ w, bf16* __restrict__ bth,
                         bf16* __restrict__ btl) {
  __shared__ float t[32][33];
  int n0 = blockIdx.x * 32, k0 = blockIdx.y * 32;
  int tx = threadIdx.x & 31, ty = threadIdx.x >> 5;
#pragma unroll
  for (int i = 0; i < 4; i++)
    t[ty + 8 * i][tx] = w[(size_t)(k0 + ty + 8 * i) * 3072 + n0 + tx];
  __syncthreads();
#pragma unroll
  for (int i = 0; i < 4; i++) {
    int r = ty + 8 * i;
    float v = t[tx][r];
    size_t o = (size_t)(n0 + r) * 1024 + k0 + tx;
    bf16 hb = (bf16)v;
    bth[o] = hb;
    btl[o] = (bf16)(v - (float)hb);
  }
}

__global__ void k_wt_out(const float* __restrict__ w, bf16* __restrict__ bt) {
  __shared__ float t[32][33];
  int n0 = blockIdx.x * 32, k0 = blockIdx.y * 32;
  int tx = threadIdx.x & 31, ty = threadIdx.x >> 5;
#pragma unroll
  for (int i = 0; i < 4; i++)
    t[ty + 8 * i][tx] = w[(size_t)(k0 + ty + 8 * i) * 1024 + n0 + tx];
  __syncthreads();
#pragma unroll
  for (int i = 0; i < 4; i++) {
    int r = ty + 8 * i;
    bt[(size_t)(n0 + r) * 1024 + k0 + tx] = (bf16)t[tx][r];
  }
}

__global__ void k_rope_tables(float* __restrict__ ct, float* __restrict__ st) {
  int i = blockIdx.x * 256 + threadIdx.x;   // 65536
  int s = i >> 5, j = i & 31;
  double invf = pow(10000.0, -(double)j / 32.0);
  double a = (double)s * invf;
  ct[i] = (float)cos(a);
  st[i] = (float)sin(a);
}

// ---------------- QKV GEMM ----------------
__global__ __launch_bounds__(256, 2) void k_gemm_qkv(
    const bf16* __restrict__ Ah, const bf16* __restrict__ Al,
    const bf16* __restrict__ Bh, const bf16* __restrict__ Bl,
    bf16* __restrict__ C) {
  const int K = 1024, N = 3072;
  __shared__ __align__(16) bf16 sAh[128 * 32];
  __shared__ __align__(16) bf16 sAl[128 * 32];
  __shared__ __align__(16) bf16 sBh[128 * 32];
  __shared__ __align__(16) bf16 sBl[128 * 32];
  int tid = threadIdx.x, lane = tid & 63, wid = tid >> 6;
  int m0 = blockIdx.x * 128, n0 = blockIdx.y * 128;
  int wm = wid >> 1, wn = wid & 1;

  f32x4 acc[4][4];
#pragma unroll
  for (int a = 0; a < 4; a++)
#pragma unroll
    for (int b = 0; b < 4; b++) acc[a][b] = (f32x4){0.f, 0.f, 0.f, 0.f};

  for (int k0 = 0; k0 < K; k0 += 32) {
#pragma unroll
    for (int p = 0; p < 2; p++) {
      int slot = p * 256 + tid;
      int row = slot >> 2, c16 = slot & 3;
      int cs = c16 ^ ((row >> 1) & 3);
      int ldsoff = (p * 256 + wid * 64) * 16;
      size_t ga = (size_t)(m0 + row) * K + k0 + cs * 8;
      size_t gb = (size_t)(n0 + row) * K + k0 + cs * 8;
      gload_lds16(Ah + ga, (char*)sAh + ldsoff);
      gload_lds16(Al + ga, (char*)sAl + ldsoff);
      gload_lds16(Bh + gb, (char*)sBh + ldsoff);
      gload_lds16(Bl + gb, (char*)sBl + ldsoff);
    }
    __syncthreads();

    bf16x8 fah[4], fal[4], fbh[4], fbl[4];
#pragma unroll
    for (int mf = 0; mf < 4; mf++) {
      int row = wm * 64 + mf * 16 + (lane & 15);
      int c16 = (lane >> 4) ^ ((row >> 1) & 3);
      int off = row * 64 + c16 * 16;
      fah[mf] = *(const bf16x8*)((const char*)sAh + off);
      fal[mf] = *(const bf16x8*)((const char*)sAl + off);
    }
#pragma unroll
    for (int nf = 0; nf < 4; nf++) {
      int row = wn * 64 + nf * 16 + (lane & 15);
      int c16 = (lane >> 4) ^ ((row >> 1) & 3);
      int off = row * 64 + c16 * 16;
      fbh[nf] = *(const bf16x8*)((const char*)sBh + off);
      fbl[nf] = *(const bf16x8*)((const char*)sBl + off);
    }
#pragma unroll
    for (int mf = 0; mf < 4; mf++)
#pragma unroll
      for (int nf = 0; nf < 4; nf++) {
        acc[mf][nf] = mfma16(fah[mf], fbh[nf], acc[mf][nf]);
        acc[mf][nf] = mfma16(fah[mf], fbl[nf], acc[mf][nf]);
        acc[mf][nf] = mfma16(fal[mf], fbh[nf], acc[mf][nf]);
      }
    __syncthreads();
  }

#pragma unroll
  for (int mf = 0; mf < 4; mf++)
#pragma unroll
    for (int nf = 0; nf < 4; nf++)
#pragma unroll
      for (int r = 0; r < 4; r++) {
        int row = m0 + wm * 64 + mf * 16 + (lane >> 4) * 4 + r;
        int col = n0 + wn * 64 + nf * 16 + (lane & 15);
        C[(size_t)row * N + col] = (bf16)acc[mf][nf][r];
      }
}

// ---------------- RoPE + scatter (Q pre-scaled by log2e/8) ----------------
__global__ void k_rope_scatter(const bf16* __restrict__ QKV,
                               const float* __restrict__ ct,
                               const float* __restrict__ st,
                               bf16* __restrict__ Q, bf16* __restrict__ Kb,
                               bf16* __restrict__ Vt) {
  __shared__ __align__(16) bf16 vt[64 * 64];
  int sblk = blockIdx.x, bh = blockIdx.y;
  int b = bh >> 4, h = bh & 15;
  int tid = threadIdx.x;
  int r = tid >> 2, c = tid & 3;
  int s = sblk * 64 + r;
  size_t rowbase = ((size_t)(b * S_LEN + s)) * 3072 + h * 192;

  bf16x8 qlo = *(const bf16x8*)(QKV + rowbase + c * 8);
  bf16x8 qhi = *(const bf16x8*)(QKV + rowbase + c * 8 + 32);
  bf16x8 klo = *(const bf16x8*)(QKV + rowbase + 64 + c * 8);
  bf16x8 khi = *(const bf16x8*)(QKV + rowbase + 64 + c * 8 + 32);
  bf16x8 vlo = *(const bf16x8*)(QKV + rowbase + 128 + c * 8);
  bf16x8 vhi = *(const bf16x8*)(QKV + rowbase + 128 + c * 8 + 32);

  bf16x8 qol, qoh, kol, koh;
#pragma unroll
  for (int j = 0; j < 8; j++) {
    float cs = ct[s * 32 + c * 8 + j], sn = st[s * 32 + c * 8 + j];
    float q1 = (float)qlo[j], q2 = (float)qhi[j];
    qol[j] = (bf16)((q1 * cs - q2 * sn) * QSCALE);
    qoh[j] = (bf16)((q2 * cs + q1 * sn) * QSCALE);
    float k1 = (float)klo[j], k2 = (float)khi[j];
    kol[j] = (bf16)(k1 * cs - k2 * sn);
    koh[j] = (bf16)(k2 * cs + k1 * sn);
  }
  size_t qb = ((size_t)bh * S_LEN + s) * 64 + c * 8;
  *(bf16x8*)(Q + qb) = qol;
  *(bf16x8*)(Q + qb + 32) = qoh;
  *(bf16x8*)(Kb + qb) = kol;
  *(bf16x8*)(Kb + qb + 32) = koh;

#pragma unroll
  for (int j = 0; j < 8; j++) {
    vt[(c * 8 + j) * 64 + r] = vlo[j];
    vt[(c * 8 + 32 + j) * 64 + r] = vhi[j];
  }
  __syncthreads();
  int d = tid >> 2, cc = tid & 3;
  size_t vb = ((size_t)bh * 64 + d) * S_LEN + sblk * 64 + cc * 16;
  *(bf16x8*)(Vt + vb) = *(const bf16x8*)(vt + d * 64 + cc * 16);
  *(bf16x8*)(Vt + vb + 8) = *(const bf16x8*)(vt + d * 64 + cc * 16 + 8);
}

// ---------------- Flash attention ----------------
// 256 thr = 4 waves; wave w owns 16 q-rows (qt*64 + w*16 + q). Full K sweep
// per block (no kv-split, no merge). sfr[8] = 32 VGPRs -> total demand ~90,
// fits launch_bounds(256,4) cap of 128: NO SPILLS (R6/R7 lesson: 512-thr +
// lb(512,4) spilled sfr -> 264 MB scratch writes, L2 thrash).
// Grid dim3(32 bh fast, 32 qt) = 1024 blocks, all co-resident (4/CU, 32KB
// LDS each): 16 waves/CU. All 32 qt of a head on one XCD -> K/V L2-hot.
// Swapped-operand S^T = mfma(K,Q) (exp2 domain), in-register P with k-slot
// permutation tau(g,j) = 16*(j>>2)+4g+(j&3) applied to BOTH PV operands
// (V read as two bf16x4 at key offsets g*4 and 16+g*4).
// K tiles (128 keys, 16KB) double-buffered in LDS; one barrier per kt.
__global__ __launch_bounds__(256, 4) void k_attn(
    const bf16* __restrict__ Q, const bf16* __restrict__ Kb,
    const bf16* __restrict__ Vt, const int* __restrict__ mask,
    bf16* __restrict__ Ctx) {
  __shared__ __align__(16) char sK[2][16384];
  int tid = threadIdx.x, lane = tid & 63, w = tid >> 6;
  int g = lane >> 4, q = lane & 15;
  int bh = blockIdx.x, qt = blockIdx.y;   // bh fast-varying: XCD/L2 locality
  int b = bh >> 4, h = bh & 15;
  int qrow = qt * 64 + w * 16 + q;

  // Q as B-operand (pre-scaled by log2e/8 upstream)
  bf16x8 bQ[2];
#pragma unroll
  for (int ks = 0; ks < 2; ks++)
    bQ[ks] = *(const bf16x8*)(Q + ((size_t)bh * S_LEN + qrow) * 64 + ks * 32 + g * 8);

  f32x4 O[4];
#pragma unroll
  for (int nd = 0; nd < 4; nd++) O[nd] = (f32x4){0.f, 0.f, 0.f, 0.f};
  float mrow = -3e38f, lrow = 0.f;

  const bf16* kbase = Kb + (size_t)bh * S_LEN * 64;
  const bf16* vbase = Vt + (size_t)bh * 64 * S_LEN;
  int db = 0;

  // stage kt=0 (128 keys x 64 d = 16KB = 1024 slots of 16B; 4 slots/thread)
#pragma unroll
  for (int p = 0; p < 4; p++) {
    int slot = p * 256 + tid;
    int row = slot >> 3, c16 = slot & 7;
    int cs = c16 ^ (row & 7);
    gload_lds16(kbase + (size_t)row * 64 + cs * 8,
                sK[0] + (p * 256 + w * 64) * 16);
  }
  __syncthreads();

  for (int kt = 0; kt < 16; kt++) {
    int k0 = kt * 128;
    if (kt < 15) {
#pragma unroll
      for (int p = 0; p < 4; p++) {
        int slot = p * 256 + tid;
        int row = slot >> 3, c16 = slot & 7;
        int cs = c16 ^ (row & 7);
        gload_lds16(kbase + (size_t)((kt + 1) * 128 + row) * 64 + cs * 8,
                    sK[db ^ 1] + (p * 256 + w * 64) * 16);
      }
    }
    const char* kl = sK[db];

    // S^T = K Q^T  (lane holds S^T[key = kf*16 + tau][q])
    f32x4 sfr[8];
#pragma unroll
    for (int kf = 0; kf < 8; kf++) sfr[kf] = (f32x4){0.f, 0.f, 0.f, 0.f};
#pragma unroll
    for (int kf = 0; kf < 8; kf++) {
#pragma unroll
      for (int ks = 0; ks < 2; ks++) {
        int row = kf * 16 + q;
        int c16 = (ks * 4 + g) ^ (row & 7);
        bf16x8 ak = *(const bf16x8*)(kl + row * 128 + c16 * 16);
        sfr[kf] = mfma16(ak, bQ[ks], sfr[kf]);
      }
    }
    // mask: fast wave-uniform skip (bench mask is all ones)
    {
      int2 mv = *(const int2*)(mask + b * S_LEN + k0 + lane * 2);
      if (!__all(mv.x & mv.y)) {
#pragma unroll
        for (int kf = 0; kf < 8; kf++) {
          int4 m4 = *(const int4*)(mask + b * S_LEN + k0 + kf * 16 + g * 4);
          int mm[4] = {m4.x, m4.y, m4.z, m4.w};
#pragma unroll
          for (int r = 0; r < 4; r++)
            if (mm[r] == 0) sfr[kf][r] = -1e30f;
        }
      }
    }
    // online softmax in exp2 domain, defer-max THR=8
    {
      float mx = -3e38f;
#pragma unroll
      for (int kf = 0; kf < 8; kf++)
#pragma unroll
        for (int r = 0; r < 4; r++) mx = fmaxf(mx, sfr[kf][r]);
      mx = fmaxf(mx, __shfl_xor(mx, 16, 64));
      mx = fmaxf(mx, __shfl_xor(mx, 32, 64));
      if (__any(mx > mrow + 8.0f)) {
        float mnew = fmaxf(mrow, mx);
        float al = exp2f(mrow - mnew);
        mrow = mnew;
        lrow *= al;
#pragma unroll
        for (int nd = 0; nd < 4; nd++)
#pragma unroll
          for (int r = 0; r < 4; r++) O[nd][r] *= al;
      }
      float ps = 0.f;
#pragma unroll
      for (int kf = 0; kf < 8; kf++)
#pragma unroll
        for (int r = 0; r < 4; r++) {
          float p0 = exp2f(sfr[kf][r] - mrow);
          sfr[kf][r] = p0;
          ps += p0;
        }
      ps += __shfl_xor(ps, 16, 64);
      ps += __shfl_xor(ps, 32, 64);
      lrow += ps;
    }

    // PV: P^T from own registers; V from L2 with MATCHING tau permutation:
    // av[j] -> key = k0 + ks*32 + 16*(j>>2) + g*4 + (j&3)  (two bf16x4 loads)
#pragma unroll
    for (int ks = 0; ks < 4; ks++) {
      bf16x8 pb;
#pragma unroll
      for (int j = 0; j < 8; j++)
        pb[j] = (bf16)sfr[2 * ks + (j >> 2)][j & 3];
#pragma unroll
      for (int nd = 0; nd < 4; nd++) {
        const bf16* vrow = vbase + (size_t)(nd * 16 + q) * S_LEN + k0 + ks * 32;
        bf16x4 v0 = *(const bf16x4*)(vrow + g * 4);
        bf16x4 v1 = *(const bf16x4*)(vrow + 16 + g * 4);
        bf16x8 av;
#pragma unroll
        for (int j = 0; j < 4; j++) { av[j] = v0[j]; av[4 + j] = v1[j]; }
        O[nd] = mfma16(av, pb, O[nd]);
      }
    }
    __syncthreads();   // drains prefetch (vmcnt0) + protects db^1 overwrite
    db ^= 1;
  }

  float inv = 1.f / lrow;
#pragma unroll
  for (int nd = 0; nd < 4; nd++) {
    bf16x4 o4;
#pragma unroll
    for (int r = 0; r < 4; r++) o4[r] = (bf16)(O[nd][r] * inv);
    *(bf16x4*)(Ctx + ((size_t)b * S_LEN + qrow) * 1024 + h * 64 + nd * 16 + g * 4) = o4;
  }
}

// ---------------- out GEMM ----------------
__global__ __launch_bounds__(256, 2) void k_gemm_out(
    const bf16* __restrict__ A, const bf16* __restrict__ Bt,
    float* __restrict__ C) {
  const int K = 1024, N = 1024;
  __shared__ __align__(16) bf16 sA[128 * 32];
  __shared__ __align__(16) bf16 sB[128 * 32];
  int tid = threadIdx.x, lane = tid & 63, wid = tid >> 6;
  int m0 = blockIdx.x * 128, n0 = blockIdx.y * 128;
  int wm = wid >> 1, wn = wid & 1;

  f32x4 acc[4][4];
#pragma unroll
  for (int a = 0; a < 4; a++)
#pragma unroll
    for (int b = 0; b < 4; b++) acc[a][b] = (f32x4){0.f, 0.f, 0.f, 0.f};

  for (int k0 = 0; k0 < K; k0 += 32) {
#pragma unroll
    for (int p = 0; p < 2; p++) {
      int slot = p * 256 + tid;
      int row = slot >> 2, c16 = slot & 3;
      int cs = c16 ^ ((row >> 1) & 3);
      int ldsoff = (p * 256 + wid * 64) * 16;
      gload_lds16(A + (size_t)(m0 + row) * K + k0 + cs * 8, (char*)sA + ldsoff);
      gload_lds16(Bt + (size_t)(n0 + row) * K + k0 + cs * 8, (char*)sB + ldsoff);
    }
    __syncthreads();
    bf16x8 fa[4], fb[4];
#pragma unroll
    for (int mf = 0; mf < 4; mf++) {
      int row = wm * 64 + mf * 16 + (lane & 15);
      int c16 = (lane >> 4) ^ ((row >> 1) & 3);
      fa[mf] = *(const bf16x8*)((const char*)sA + row * 64 + c16 * 16);
    }
#pragma unroll
    for (int nf = 0; nf < 4; nf++) {
      int row = wn * 64 + nf * 16 + (lane & 15);
      int c16 = (lane >> 4) ^ ((row >> 1) & 3);
      fb[nf] = *(const bf16x8*)((const char*)sB + row * 64 + c16 * 16);
    }
#pragma unroll
    for (int mf = 0; mf < 4; mf++)
#pragma unroll
      for (int nf = 0; nf < 4; nf++)
        acc[mf][nf] = mfma16(fa[mf], fb[nf], acc[mf][nf]);
    __syncthreads();
  }
#pragma unroll
  for (int mf = 0; mf < 4; mf++)
#pragma unroll
    for (int nf = 0; nf < 4; nf++)
#pragma unroll
      for (int r = 0; r < 4; r++) {
        int row = m0 + wm * 64 + mf * 16 + (lane >> 4) * 4 + r;
        int col = n0 + wn * 64 + nf * 16 + (lane & 15);
        C[(size_t)row * N + col] = acc[mf][nf][r];
      }
}

// ---------------- launch ----------------
extern "C" void kernel_launch(void* const* d_in, const int* in_sizes, int n_in,
                              void* d_out, int out_size, void* d_ws, size_t ws_size,
                              hipStream_t stream) {
  const float* x = (const float*)d_in[0];
  const int* mask = (const int*)d_in[1];
  const float* wqkv = (const float*)d_in[2];
  const float* wout = (const float*)d_in[3];
  float* out = (float*)d_out;
  char* ws = (char*)d_ws;

  bf16* Xh  = (bf16*)(ws + 0);
  bf16* Xl  = (bf16*)(ws + 8388608);
  bf16* Wqh = (bf16*)(ws + 16777216);
  bf16* Wql = (bf16*)(ws + 23068672);
  bf16* Wo  = (bf16*)(ws + 29360128);
  bf16* QKV = (bf16*)(ws + 31457280);
  bf16* Qb  = (bf16*)(ws + 56623104);
  bf16* Kb  = (bf16*)(ws + 65011712);
  bf16* Vt  = (bf16*)(ws + 73400320);
  bf16* Ctx = (bf16*)(ws + 81788928);
  float* ct = (float*)(ws + 90177536);
  float* st = (float*)(ws + 90439680);

  k_split_x<<<4096, 256, 0, stream>>>(x, Xh, Xl);
  k_wt_qkv<<<dim3(96, 32), 256, 0, stream>>>(wqkv, Wqh, Wql);
  k_wt_out<<<dim3(32, 32), 256, 0, stream>>>(wout, Wo);
  k_rope_tables<<<256, 256, 0, stream>>>(ct, st);
  k_gemm_qkv<<<dim3(32, 24), 256, 0, stream>>>(Xh, Xl, Wqh, Wql, QKV);
  k_rope_scatter<<<dim3(32, 32), 256, 0, stream>>>(QKV, ct, st, Qb, Kb, Vt);
  k_attn<<<dim3(32, 32), 256, 0, stream>>>(Qb, Kb, Vt, mask, Ctx);
  k_gemm_out<<<dim3(32, 8), 256, 0, stream>>>(Ctx, Wo, out);
}

// Round 9
// 259.771 us; speedup vs baseline: 1.6195x; 1.6195x over previous
//
#include <hip/hip_runtime.h>
#include <hip/hip_bf16.h>
#include <math.h>
#include <stdint.h>

// MHA pipeline: split_x + transpose weights (hi/lo bf16) + rope tables ->
// split QKV GEMM (3-term bf16 MFMA) -> rope+scatter (Q pre-scaled log2e/8) ->
// flash attention (4 waves x 32 q-rows, K dbuf gload_lds, V reg-staged->LDS,
// in-register P, bh-fast grid) -> out GEMM.

typedef __bf16 bf16;
typedef __bf16 bf16x8 __attribute__((ext_vector_type(8)));
typedef __bf16 bf16x4 __attribute__((ext_vector_type(4)));
typedef float f32x4 __attribute__((ext_vector_type(4)));

#define AS1 __attribute__((address_space(1)))
#define AS3 __attribute__((address_space(3)))

__device__ __forceinline__ void gload_lds16(const void* g, void* l) {
  __builtin_amdgcn_global_load_lds((const AS1 void*)g, (AS3 void*)l, 16, 0, 0);
}

__device__ __forceinline__ f32x4 mfma16(bf16x8 a, bf16x8 b, f32x4 c) {
  return __builtin_amdgcn_mfma_f32_16x16x32_bf16(a, b, c, 0, 0, 0);
}

#define S_LEN 2048
#define QSCALE 0.1803368801111144f  /* log2(e)/8 */

// ---------------- prep kernels ----------------

__global__ void k_split_x(const float* __restrict__ x, bf16* __restrict__ xh,
                          bf16* __restrict__ xl) {
  int i = blockIdx.x * 256 + threadIdx.x;
  float4 v = ((const float4*)x)[i];
  float vv[4] = {v.x, v.y, v.z, v.w};
  bf16x4 h, l;
#pragma unroll
  for (int j = 0; j < 4; j++) {
    bf16 hb = (bf16)vv[j];
    h[j] = hb;
    l[j] = (bf16)(vv[j] - (float)hb);
  }
  ((bf16x4*)xh)[i] = h;
  ((bf16x4*)xl)[i] = l;
}

__global__ void k_wt_qkv(const float* __restrict__ w, bf16* __restrict__ bth,
                         bf16* __restrict__ btl) {
  __shared__ float t[32][33];
  int n0 = blockIdx.x * 32, k0 = blockIdx.y * 32;
  int tx = threadIdx.x & 31, ty = threadIdx.x >> 5;
#pragma unroll
  for (int i = 0; i < 4; i++)
    t[ty + 8 * i][tx] = w[(size_t)(k0 + ty + 8 * i) * 3072 + n0 + tx];
  __syncthreads();
#pragma unroll
  for (int i = 0; i < 4; i++) {
    int r = ty + 8 * i;
    float v = t[tx][r];
    size_t o = (size_t)(n0 + r) * 1024 + k0 + tx;
    bf16 hb = (bf16)v;
    bth[o] = hb;
    btl[o] = (bf16)(v - (float)hb);
  }
}

__global__ void k_wt_out(const float* __restrict__ w, bf16* __restrict__ bt) {
  __shared__ float t[32][33];
  int n0 = blockIdx.x * 32, k0 = blockIdx.y * 32;
  int tx = threadIdx.x & 31, ty = threadIdx.x >> 5;
#pragma unroll
  for (int i = 0; i < 4; i++)
    t[ty + 8 * i][tx] = w[(size_t)(k0 + ty + 8 * i) * 1024 + n0 + tx];
  __syncthreads();
#pragma unroll
  for (int i = 0; i < 4; i++) {
    int r = ty + 8 * i;
    bt[(size_t)(n0 + r) * 1024 + k0 + tx] = (bf16)t[tx][r];
  }
}

__global__ void k_rope_tables(float* __restrict__ ct, float* __restrict__ st) {
  int i = blockIdx.x * 256 + threadIdx.x;   // 65536
  int s = i >> 5, j = i & 31;
  double invf = pow(10000.0, -(double)j / 32.0);
  double a = (double)s * invf;
  ct[i] = (float)cos(a);
  st[i] = (float)sin(a);
}

// ---------------- QKV GEMM ----------------
__global__ __launch_bounds__(256, 2) void k_gemm_qkv(
    const bf16* __restrict__ Ah, const bf16* __restrict__ Al,
    const bf16* __restrict__ Bh, const bf16* __restrict__ Bl,
    bf16* __restrict__ C) {
  const int K = 1024, N = 3072;
  __shared__ __align__(16) bf16 sAh[128 * 32];
  __shared__ __align__(16) bf16 sAl[128 * 32];
  __shared__ __align__(16) bf16 sBh[128 * 32];
  __shared__ __align__(16) bf16 sBl[128 * 32];
  int tid = threadIdx.x, lane = tid & 63, wid = tid >> 6;
  int m0 = blockIdx.x * 128, n0 = blockIdx.y * 128;
  int wm = wid >> 1, wn = wid & 1;

  f32x4 acc[4][4];
#pragma unroll
  for (int a = 0; a < 4; a++)
#pragma unroll
    for (int b = 0; b < 4; b++) acc[a][b] = (f32x4){0.f, 0.f, 0.f, 0.f};

  for (int k0 = 0; k0 < K; k0 += 32) {
#pragma unroll
    for (int p = 0; p < 2; p++) {
      int slot = p * 256 + tid;
      int row = slot >> 2, c16 = slot & 3;
      int cs = c16 ^ ((row >> 1) & 3);
      int ldsoff = (p * 256 + wid * 64) * 16;
      size_t ga = (size_t)(m0 + row) * K + k0 + cs * 8;
      size_t gb = (size_t)(n0 + row) * K + k0 + cs * 8;
      gload_lds16(Ah + ga, (char*)sAh + ldsoff);
      gload_lds16(Al + ga, (char*)sAl + ldsoff);
      gload_lds16(Bh + gb, (char*)sBh + ldsoff);
      gload_lds16(Bl + gb, (char*)sBl + ldsoff);
    }
    __syncthreads();

    bf16x8 fah[4], fal[4], fbh[4], fbl[4];
#pragma unroll
    for (int mf = 0; mf < 4; mf++) {
      int row = wm * 64 + mf * 16 + (lane & 15);
      int c16 = (lane >> 4) ^ ((row >> 1) & 3);
      int off = row * 64 + c16 * 16;
      fah[mf] = *(const bf16x8*)((const char*)sAh + off);
      fal[mf] = *(const bf16x8*)((const char*)sAl + off);
    }
#pragma unroll
    for (int nf = 0; nf < 4; nf++) {
      int row = wn * 64 + nf * 16 + (lane & 15);
      int c16 = (lane >> 4) ^ ((row >> 1) & 3);
      int off = row * 64 + c16 * 16;
      fbh[nf] = *(const bf16x8*)((const char*)sBh + off);
      fbl[nf] = *(const bf16x8*)((const char*)sBl + off);
    }
#pragma unroll
    for (int mf = 0; mf < 4; mf++)
#pragma unroll
      for (int nf = 0; nf < 4; nf++) {
        acc[mf][nf] = mfma16(fah[mf], fbh[nf], acc[mf][nf]);
        acc[mf][nf] = mfma16(fah[mf], fbl[nf], acc[mf][nf]);
        acc[mf][nf] = mfma16(fal[mf], fbh[nf], acc[mf][nf]);
      }
    __syncthreads();
  }

#pragma unroll
  for (int mf = 0; mf < 4; mf++)
#pragma unroll
    for (int nf = 0; nf < 4; nf++)
#pragma unroll
      for (int r = 0; r < 4; r++) {
        int row = m0 + wm * 64 + mf * 16 + (lane >> 4) * 4 + r;
        int col = n0 + wn * 64 + nf * 16 + (lane & 15);
        C[(size_t)row * N + col] = (bf16)acc[mf][nf][r];
      }
}

// ---------------- RoPE + scatter (Q pre-scaled by log2e/8) ----------------
__global__ void k_rope_scatter(const bf16* __restrict__ QKV,
                               const float* __restrict__ ct,
                               const float* __restrict__ st,
                               bf16* __restrict__ Q, bf16* __restrict__ Kb,
                               bf16* __restrict__ Vt) {
  __shared__ __align__(16) bf16 vt[64 * 64];
  int sblk = blockIdx.x, bh = blockIdx.y;
  int b = bh >> 4, h = bh & 15;
  int tid = threadIdx.x;
  int r = tid >> 2, c = tid & 3;
  int s = sblk * 64 + r;
  size_t rowbase = ((size_t)(b * S_LEN + s)) * 3072 + h * 192;

  bf16x8 qlo = *(const bf16x8*)(QKV + rowbase + c * 8);
  bf16x8 qhi = *(const bf16x8*)(QKV + rowbase + c * 8 + 32);
  bf16x8 klo = *(const bf16x8*)(QKV + rowbase + 64 + c * 8);
  bf16x8 khi = *(const bf16x8*)(QKV + rowbase + 64 + c * 8 + 32);
  bf16x8 vlo = *(const bf16x8*)(QKV + rowbase + 128 + c * 8);
  bf16x8 vhi = *(const bf16x8*)(QKV + rowbase + 128 + c * 8 + 32);

  bf16x8 qol, qoh, kol, koh;
#pragma unroll
  for (int j = 0; j < 8; j++) {
    float cs = ct[s * 32 + c * 8 + j], sn = st[s * 32 + c * 8 + j];
    float q1 = (float)qlo[j], q2 = (float)qhi[j];
    qol[j] = (bf16)((q1 * cs - q2 * sn) * QSCALE);
    qoh[j] = (bf16)((q2 * cs + q1 * sn) * QSCALE);
    float k1 = (float)klo[j], k2 = (float)khi[j];
    kol[j] = (bf16)(k1 * cs - k2 * sn);
    koh[j] = (bf16)(k2 * cs + k1 * sn);
  }
  size_t qb = ((size_t)bh * S_LEN + s) * 64 + c * 8;
  *(bf16x8*)(Q + qb) = qol;
  *(bf16x8*)(Q + qb + 32) = qoh;
  *(bf16x8*)(Kb + qb) = kol;
  *(bf16x8*)(Kb + qb + 32) = koh;

#pragma unroll
  for (int j = 0; j < 8; j++) {
    vt[(c * 8 + j) * 64 + r] = vlo[j];
    vt[(c * 8 + 32 + j) * 64 + r] = vhi[j];
  }
  __syncthreads();
  int d = tid >> 2, cc = tid & 3;
  size_t vb = ((size_t)bh * 64 + d) * S_LEN + sblk * 64 + cc * 16;
  *(bf16x8*)(Vt + vb) = *(const bf16x8*)(vt + d * 64 + cc * 16);
  *(bf16x8*)(Vt + vb + 8) = *(const bf16x8*)(vt + d * 64 + cc * 16 + 8);
}

// ---------------- Flash attention ----------------
// 256 thr = 4 waves; wave w owns 32 q-rows (qt*128 + w*32 + mf*16 + q).
// Grid dim3(32 bh fast, 16 qt) = 512 blocks; all qt of a head on one XCD.
// K tiles: double-buffered LDS via global_load_lds (prefetch at kt start,
// drained at post-PV barrier -> hidden under 64 MFMA + softmax).
// V tile: single LDS buffer, REG-STAGED (T14): global->reg issued at kt
// start (hidden), reg->ds_write after the post-PV barrier -> no exposed
// L2 latency. V LDS layout [d][key] with c16 ^= (d&7); PV reads two
// ds_read_b64 at key offsets matching tau(g,j)=16*(j>>2)+4g+(j&3), the
// SAME permutation as the in-register P fragment (both-operands rule).
// lb(256,2): VGPR cap 256 -> allocator never forced to spill (R6/R7
// lesson: forced cap 128 -> 264 MB scratch). LDS 48 KB -> 3 blocks/CU
// if VGPR <= 170.
__global__ __launch_bounds__(256, 2) void k_attn(
    const bf16* __restrict__ Q, const bf16* __restrict__ Kb,
    const bf16* __restrict__ Vt, const int* __restrict__ mask,
    bf16* __restrict__ Ctx) {
  __shared__ __align__(16) char sK[2][16384];
  __shared__ __align__(16) char sV[16384];
  int tid = threadIdx.x, lane = tid & 63, w = tid >> 6;
  int g = lane >> 4, q = lane & 15;
  int bh = blockIdx.x, qt = blockIdx.y;   // bh fast-varying: XCD/L2 locality
  int b = bh >> 4, h = bh & 15;
  int q0 = qt * 128 + w * 32;

  // Q as B-operand (pre-scaled by log2e/8 upstream)
  bf16x8 bQ[2][2];
#pragma unroll
  for (int mf = 0; mf < 2; mf++)
#pragma unroll
    for (int ks = 0; ks < 2; ks++)
      bQ[mf][ks] = *(const bf16x8*)(Q + ((size_t)bh * S_LEN + q0 + mf * 16 + q) * 64 +
                                    ks * 32 + g * 8);

  f32x4 O[2][4];
  float mrow[2], lrow[2];
#pragma unroll
  for (int mf = 0; mf < 2; mf++) {
#pragma unroll
    for (int nd = 0; nd < 4; nd++) O[mf][nd] = (f32x4){0.f, 0.f, 0.f, 0.f};
    mrow[mf] = -3e38f;
    lrow[mf] = 0.f;
  }

  const bf16* kbase = Kb + (size_t)bh * S_LEN * 64;
  const bf16* vbase = Vt + (size_t)bh * 64 * S_LEN;

  // prologue: K[0] -> sK[0] (gload_lds), V[0] -> regs -> sV
#pragma unroll
  for (int p = 0; p < 4; p++) {
    int slot = p * 256 + tid;
    int row = slot >> 3, c16 = slot & 7;
    int cs = c16 ^ (row & 7);
    gload_lds16(kbase + (size_t)row * 64 + cs * 8, sK[0] + (p * 256 + w * 64) * 16);
  }
  bf16x8 vst[4];
#pragma unroll
  for (int p = 0; p < 4; p++) {
    int slot = p * 256 + tid;
    int row = slot >> 4, c16 = slot & 15;
    int cs = c16 ^ (row & 7);
    vst[p] = *(const bf16x8*)(vbase + (size_t)row * S_LEN + cs * 8);
  }
#pragma unroll
  for (int p = 0; p < 4; p++)
    *(bf16x8*)(sV + (p * 256 + tid) * 16) = vst[p];
  __syncthreads();

  int db = 0;
  for (int kt = 0; kt < 16; kt++) {
    int k0 = kt * 128;
    if (kt < 15) {
      // issue next K tile -> LDS (async) and next V tile -> regs; both
      // consumed only after the post-PV barrier: latency fully hidden.
#pragma unroll
      for (int p = 0; p < 4; p++) {
        int slot = p * 256 + tid;
        int row = slot >> 3, c16 = slot & 7;
        int cs = c16 ^ (row & 7);
        gload_lds16(kbase + (size_t)((kt + 1) * 128 + row) * 64 + cs * 8,
                    sK[db ^ 1] + (p * 256 + w * 64) * 16);
      }
#pragma unroll
      for (int p = 0; p < 4; p++) {
        int slot = p * 256 + tid;
        int row = slot >> 4, c16 = slot & 15;
        int cs = c16 ^ (row & 7);
        vst[p] = *(const bf16x8*)(vbase + (size_t)row * S_LEN + (kt + 1) * 128 + cs * 8);
      }
    }
    const char* kl = sK[db];

    // S^T = K Q^T  (lane holds S^T[key = kf*16 + 4g + r][q0 + mf*16 + q])
    f32x4 sfr[2][8];
#pragma unroll
    for (int mf = 0; mf < 2; mf++)
#pragma unroll
      for (int kf = 0; kf < 8; kf++) sfr[mf][kf] = (f32x4){0.f, 0.f, 0.f, 0.f};
#pragma unroll
    for (int kf = 0; kf < 8; kf++) {
#pragma unroll
      for (int ks = 0; ks < 2; ks++) {
        int row = kf * 16 + q;
        int c16 = (ks * 4 + g) ^ (row & 7);
        bf16x8 ak = *(const bf16x8*)(kl + row * 128 + c16 * 16);
        sfr[0][kf] = mfma16(ak, bQ[0][ks], sfr[0][kf]);
        sfr[1][kf] = mfma16(ak, bQ[1][ks], sfr[1][kf]);
      }
    }
    // mask: fast wave-uniform skip (bench mask is all ones)
    {
      int2 mv = *(const int2*)(mask + b * S_LEN + k0 + lane * 2);
      if (!__all(mv.x & mv.y)) {
#pragma unroll
        for (int kf = 0; kf < 8; kf++) {
          int4 m4 = *(const int4*)(mask + b * S_LEN + k0 + kf * 16 + g * 4);
          int mm[4] = {m4.x, m4.y, m4.z, m4.w};
#pragma unroll
          for (int r = 0; r < 4; r++)
            if (mm[r] == 0) { sfr[0][kf][r] = -1e30f; sfr[1][kf][r] = -1e30f; }
        }
      }
    }
    // online softmax in exp2 domain, defer-max THR=8
#pragma unroll
    for (int mf = 0; mf < 2; mf++) {
      float mx = -3e38f;
#pragma unroll
      for (int kf = 0; kf < 8; kf++)
#pragma unroll
        for (int r = 0; r < 4; r++) mx = fmaxf(mx, sfr[mf][kf][r]);
      mx = fmaxf(mx, __shfl_xor(mx, 16, 64));
      mx = fmaxf(mx, __shfl_xor(mx, 32, 64));
      if (__any(mx > mrow[mf] + 8.0f)) {
        float mnew = fmaxf(mrow[mf], mx);
        float al = exp2f(mrow[mf] - mnew);
        mrow[mf] = mnew;
        lrow[mf] *= al;
#pragma unroll
        for (int nd = 0; nd < 4; nd++)
#pragma unroll
          for (int r = 0; r < 4; r++) O[mf][nd][r] *= al;
      }
      float ps = 0.f;
#pragma unroll
      for (int kf = 0; kf < 8; kf++)
#pragma unroll
        for (int r = 0; r < 4; r++) {
          float p0 = exp2f(sfr[mf][kf][r] - mrow[mf]);
          sfr[mf][kf][r] = p0;
          ps += p0;
        }
      ps += __shfl_xor(ps, 16, 64);
      ps += __shfl_xor(ps, 32, 64);
      lrow[mf] += ps;
    }

    // PV: P^T from own registers; V from sV with MATCHING tau permutation:
    // av[j] -> key = ks*32 + 16*(j>>2) + g*4 + (j&3)  (two ds_read_b64)
#pragma unroll
    for (int ks = 0; ks < 4; ks++) {
      bf16x8 pb[2];
#pragma unroll
      for (int mf = 0; mf < 2; mf++)
#pragma unroll
        for (int j = 0; j < 8; j++)
          pb[mf][j] = (bf16)sfr[mf][2 * ks + (j >> 2)][j & 3];
#pragma unroll
      for (int nd = 0; nd < 4; nd++) {
        int row = nd * 16 + q;
        int u1 = (ks * 4 + (g >> 1)) ^ (row & 7);
        int u2 = (ks * 4 + (g >> 1) + 2) ^ (row & 7);
        const char* vr = sV + row * 256 + ((g & 1) << 3);
        bf16x4 v0 = *(const bf16x4*)(vr + (u1 << 4));
        bf16x4 v1 = *(const bf16x4*)(vr + (u2 << 4));
        bf16x8 av;
#pragma unroll
        for (int j = 0; j < 4; j++) { av[j] = v0[j]; av[4 + j] = v1[j]; }
        O[0][nd] = mfma16(av, pb[0], O[0][nd]);
        O[1][nd] = mfma16(av, pb[1], O[1][nd]);
      }
    }
    __syncthreads();   // A: PV done everywhere; drains K prefetch + V reg loads
    if (kt < 15) {
#pragma unroll
      for (int p = 0; p < 4; p++)
        *(bf16x8*)(sV + (p * 256 + tid) * 16) = vst[p];
    }
    __syncthreads();   // B: sV[kt+1] visible to all waves
    db ^= 1;
  }

#pragma unroll
  for (int mf = 0; mf < 2; mf++) {
    float inv = 1.f / lrow[mf];
    int srow = q0 + mf * 16 + q;
#pragma unroll
    for (int nd = 0; nd < 4; nd++) {
      bf16x4 o4;
#pragma unroll
      for (int r = 0; r < 4; r++) o4[r] = (bf16)(O[mf][nd][r] * inv);
      *(bf16x4*)(Ctx + ((size_t)b * S_LEN + srow) * 1024 + h * 64 + nd * 16 + g * 4) = o4;
    }
  }
}

// ---------------- out GEMM ----------------
__global__ __launch_bounds__(256, 2) void k_gemm_out(
    const bf16* __restrict__ A, const bf16* __restrict__ Bt,
    float* __restrict__ C) {
  const int K = 1024, N = 1024;
  __shared__ __align__(16) bf16 sA[128 * 32];
  __shared__ __align__(16) bf16 sB[128 * 32];
  int tid = threadIdx.x, lane = tid & 63, wid = tid >> 6;
  int m0 = blockIdx.x * 128, n0 = blockIdx.y * 128;
  int wm = wid >> 1, wn = wid & 1;

  f32x4 acc[4][4];
#pragma unroll
  for (int a = 0; a < 4; a++)
#pragma unroll
    for (int b = 0; b < 4; b++) acc[a][b] = (f32x4){0.f, 0.f, 0.f, 0.f};

  for (int k0 = 0; k0 < K; k0 += 32) {
#pragma unroll
    for (int p = 0; p < 2; p++) {
      int slot = p * 256 + tid;
      int row = slot >> 2, c16 = slot & 3;
      int cs = c16 ^ ((row >> 1) & 3);
      int ldsoff = (p * 256 + wid * 64) * 16;
      gload_lds16(A + (size_t)(m0 + row) * K + k0 + cs * 8, (char*)sA + ldsoff);
      gload_lds16(Bt + (size_t)(n0 + row) * K + k0 + cs * 8, (char*)sB + ldsoff);
    }
    __syncthreads();
    bf16x8 fa[4], fb[4];
#pragma unroll
    for (int mf = 0; mf < 4; mf++) {
      int row = wm * 64 + mf * 16 + (lane & 15);
      int c16 = (lane >> 4) ^ ((row >> 1) & 3);
      fa[mf] = *(const bf16x8*)((const char*)sA + row * 64 + c16 * 16);
    }
#pragma unroll
    for (int nf = 0; nf < 4; nf++) {
      int row = wn * 64 + nf * 16 + (lane & 15);
      int c16 = (lane >> 4) ^ ((row >> 1) & 3);
      fb[nf] = *(const bf16x8*)((const char*)sB + row * 64 + c16 * 16);
    }
#pragma unroll
    for (int mf = 0; mf < 4; mf++)
#pragma unroll
      for (int nf = 0; nf < 4; nf++)
        acc[mf][nf] = mfma16(fa[mf], fb[nf], acc[mf][nf]);
    __syncthreads();
  }
#pragma unroll
  for (int mf = 0; mf < 4; mf++)
#pragma unroll
    for (int nf = 0; nf < 4; nf++)
#pragma unroll
      for (int r = 0; r < 4; r++) {
        int row = m0 + wm * 64 + mf * 16 + (lane >> 4) * 4 + r;
        int col = n0 + wn * 64 + nf * 16 + (lane & 15);
        C[(size_t)row * N + col] = acc[mf][nf][r];
      }
}

// ---------------- launch ----------------
extern "C" void kernel_launch(void* const* d_in, const int* in_sizes, int n_in,
                              void* d_out, int out_size, void* d_ws, size_t ws_size,
                              hipStream_t stream) {
  const float* x = (const float*)d_in[0];
  const int* mask = (const int*)d_in[1];
  const float* wqkv = (const float*)d_in[2];
  const float* wout = (const float*)d_in[3];
  float* out = (float*)d_out;
  char* ws = (char*)d_ws;

  bf16* Xh  = (bf16*)(ws + 0);
  bf16* Xl  = (bf16*)(ws + 8388608);
  bf16* Wqh = (bf16*)(ws + 16777216);
  bf16* Wql = (bf16*)(ws + 23068672);
  bf16* Wo  = (bf16*)(ws + 29360128);
  bf16* QKV = (bf16*)(ws + 31457280);
  bf16* Qb  = (bf16*)(ws + 56623104);
  bf16* Kb  = (bf16*)(ws + 65011712);
  bf16* Vt  = (bf16*)(ws + 73400320);
  bf16* Ctx = (bf16*)(ws + 81788928);
  float* ct = (float*)(ws + 90177536);
  float* st = (float*)(ws + 90439680);

  k_split_x<<<4096, 256, 0, stream>>>(x, Xh, Xl);
  k_wt_qkv<<<dim3(96, 32), 256, 0, stream>>>(wqkv, Wqh, Wql);
  k_wt_out<<<dim3(32, 32), 256, 0, stream>>>(wout, Wo);
  k_rope_tables<<<256, 256, 0, stream>>>(ct, st);
  k_gemm_qkv<<<dim3(32, 24), 256, 0, stream>>>(Xh, Xl, Wqh, Wql, QKV);
  k_rope_scatter<<<dim3(32, 32), 256, 0, stream>>>(QKV, ct, st, Qb, Kb, Vt);
  k_attn<<<dim3(32, 16), 256, 0, stream>>>(Qb, Kb, Vt, mask, Ctx);
  k_gemm_out<<<dim3(32, 8), 256, 0, stream>>>(Ctx, Wo, out);
}